// Round 11
// baseline (292.714 us; speedup 1.0000x reference)
//
#include <hip/hip_runtime.h>
#include <math.h>

// Problem dims
#define BL    6
#define CCH   64
#define C3    192
#define L2    1024
#define DIC   128
#define NST   16
#define K4    4
#define PSTR  1088   // padded plane stride: 34 rows * 32 cols
#define NCH   32     // scan chunks per sequence (32 steps each)

#define LOG2E 1.44269504088896340736f
#define LN2C  0.69314718055994530942f

typedef float f2 __attribute__((ext_vector_type(2)));
__device__ __forceinline__ f2 mkf2(float a, float b){ f2 r; r.x=a; r.y=b; return r; }
__device__ __forceinline__ f2 fma2(f2 a, float b, f2 c){
  f2 bb; bb.x=b; bb.y=b;
  return __builtin_elementwise_fma(a, bb, c);
}

__device__ __forceinline__ float fexp(float x){ return __builtin_amdgcn_exp2f(x*LOG2E); }
__device__ __forceinline__ float fsilu(float x){ return x * __builtin_amdgcn_rcpf(1.f + fexp(-x)); }
__device__ __forceinline__ float fsoftplus(float x){
  if (x > 20.f) return x;
  return __builtin_amdgcn_logf(1.f + fexp(x)) * LN2C;
}
__device__ __forceinline__ float fgelu(float x){
  return 0.5f*x*(1.f + erff(x*0.70710678118654752440f));
}

// ---------------- k1: per-pixel LN + concat; GN1 partials. 1536 blocks (4 px each).
__global__ __launch_bounds__(256) void k_ln2d(const float* __restrict__ img,
    const float* __restrict__ dz, const float* __restrict__ sg,
    const float* __restrict__ g, const float* __restrict__ b, float* __restrict__ x3c,
    float* __restrict__ psum1, float* __restrict__ psq1){
  __shared__ float ps[4][4], pq[4][4], gs[4], gq[4];
  int s = blockIdx.x >> 8;
  int pg = blockIdx.x & 255;
  int tid = threadIdx.x;
  int px = tid & 3; int c = tid >> 2;     // 64 channels, 1 per thread
  int wv = tid >> 6; int lane = tid & 63;
  int p = pg*4 + px;
  int bsmp = s/3;
  const float* fr = img + (size_t)s*CCH*L2;
  float v = fr[c*L2 + p];
  float sm = v, sq = v*v;
  sm += __shfl_xor(sm,4,64);  sq += __shfl_xor(sq,4,64);
  sm += __shfl_xor(sm,8,64);  sq += __shfl_xor(sq,8,64);
  sm += __shfl_xor(sm,16,64); sq += __shfl_xor(sq,16,64);
  sm += __shfl_xor(sm,32,64); sq += __shfl_xor(sq,32,64);
  if (lane < 4){ ps[wv][lane]=sm; pq[wv][lane]=sq; }
  __syncthreads();
  sm = ps[0][px]+ps[1][px]+ps[2][px]+ps[3][px];
  sq = pq[0][px]+pq[1][px]+pq[2][px]+pq[3][px];
  float mean = sm*(1.f/CCH); float var = sq*(1.f/CCH)-mean*mean;
  float rs = rsqrtf(var + 1e-6f);
  float* o = x3c + (size_t)s*C3*L2;
  const float* dzp = dz + (size_t)bsmp*CCH*L2;
  const float* sgp = sg + (size_t)bsmp*CCH*L2;
  float dzv = dzp[c*L2+p];
  float nv  = (v-mean)*rs*g[c] + b[c];
  float sgv = sgp[c*L2+p];
  o[c*L2+p] = dzv;
  o[(CCH+c)*L2+p] = nv;
  o[(2*CCH+c)*L2+p] = sgv;
  float gsm = dzv+nv+sgv, gsq = dzv*dzv+nv*nv+sgv*sgv;
  for (int m=1;m<64;m<<=1){ gsm+=__shfl_xor(gsm,m,64); gsq+=__shfl_xor(gsq,m,64); }
  if (lane==0){ gs[wv]=gsm; gq[wv]=gsq; }
  __syncthreads();
  if (tid==0){
    psum1[blockIdx.x] = gs[0]+gs[1]+gs[2]+gs[3];
    psq1 [blockIdx.x] = gq[0]+gq[1]+gq[2]+gq[3];
  }
}

// ---------------- k2: MERGED gnact1 (blocks 0..1151) + skip 1x1 (blocks 1152..1535)
__global__ __launch_bounds__(256) void k_gnact1_skip(const float* __restrict__ x3c,
    const float* __restrict__ psum, const float* __restrict__ psq,
    const float* __restrict__ g, const float* __restrict__ b,
    const float* __restrict__ wsk,
    float* __restrict__ xact1, float* __restrict__ part){
  int bx = blockIdx.x;
  int tid = threadIdx.x;
  if (bx < 1152){
    int s = bx / C3; int c = bx % C3;
    float sm=0.f, sq=0.f;
    for (int i=0;i<256;++i){ sm += psum[s*256+i]; sq += psq[s*256+i]; }
    float mean = sm*(1.f/(C3*L2));
    float var = sq*(1.f/(C3*L2)) - mean*mean;
    float rs = rsqrtf(var + 1e-5f);
    float gc = g[c]*rs; float bc = b[c] - mean*rs*g[c];
    float4 v = *(const float4*)(x3c + (size_t)bx*1024 + tid*4);
    float4 o; o.x = fsilu(v.x*gc+bc); o.y = fsilu(v.y*gc+bc);
    o.z = fsilu(v.z*gc+bc); o.w = fsilu(v.w*gc+bc);
    float* pl = xact1 + (size_t)bx*PSTR;
    *(float4*)(pl + 32 + tid*4) = o;
    float4 z4 = make_float4(0.f,0.f,0.f,0.f);
    if (tid < 8)  *(float4*)(pl + tid*4) = z4;
    else if (tid < 16) *(float4*)(pl + 1056 + (tid-8)*4) = z4;
  } else {
    // skip 1x1 (2 roles x 96 ci), packed over co pair
    int t = bx - 1152;
    int role = t & 1; int cop = (t>>1)&31; int s = t >> 6;
    int co0 = cop*2, co1 = co0+1;
    int row = tid>>3; int q = tid&7; int col0 = q*4;
    int p = row*32+col0;
    f2 a[4];
    #pragma unroll
    for (int i=0;i<4;++i){ a[i].x=0.f; a[i].y=0.f; }
    int ci0 = role*96;
    const float* x3 = x3c + ((size_t)s*C3 + ci0)*L2 + p;
    const float* w0p = wsk + co0*C3 + ci0;
    const float* w1p = wsk + co1*C3 + ci0;
    #pragma unroll 4
    for (int ci=0; ci<96; ++ci){
      float4 v = *(const float4*)(x3 + (size_t)ci*L2);
      f2 w = mkf2(w0p[ci], w1p[ci]);
      a[0] = fma2(w, v.x, a[0]);
      a[1] = fma2(w, v.y, a[1]);
      a[2] = fma2(w, v.z, a[2]);
      a[3] = fma2(w, v.w, a[3]);
    }
    float* pp = part + (size_t)(4+role)*(BL*CCH*L2) + ((size_t)s*CCH+co0)*L2 + p;
    *(float4*)pp = make_float4(a[0].x,a[1].x,a[2].x,a[3].x);
    *(float4*)(pp+L2) = make_float4(a[0].y,a[1].y,a[2].y,a[3].y);
  }
}

// ---------------- gnact2: half-plane per block, 768 blocks
__global__ __launch_bounds__(256) void k_gnact_pad(const float* __restrict__ x,
    const float* __restrict__ psum, const float* __restrict__ psq,
    const float* __restrict__ g, const float* __restrict__ b,
    int ch, int parts, float inv_n, float eps, float* __restrict__ out){
  int bx0 = blockIdx.x >> 1; int half = blockIdx.x & 1;
  int s = bx0 / ch; int c = bx0 % ch;
  int tid = threadIdx.x;
  float sm=0.f, sq=0.f;
  for (int i=0;i<parts;++i){ sm += psum[s*parts+i]; sq += psq[s*parts+i]; }
  float mean = sm*inv_n;
  float var = sq*inv_n - mean*mean;
  float rs = rsqrtf(var + eps);
  float gc = g[c]*rs; float bc = b[c] - mean*rs*g[c];
  float2 v = *(const float2*)(x + (size_t)bx0*1024 + half*512 + tid*2);
  float2 o; o.x = fsilu(v.x*gc+bc); o.y = fsilu(v.y*gc+bc);
  float* pl = out + (size_t)bx0*PSTR;
  *(float2*)(pl + 32 + half*512 + tid*2) = o;
  float2 z2 = make_float2(0.f,0.f);
  if (half == 0){
    if (tid < 16) *(float2*)(pl + tid*2) = z2;
  } else {
    if (tid < 16) *(float2*)(pl + 1056 + tid*2) = z2;
  }
}

// packed conv helpers: a[4] = (co0,co1) accumulators per px
__device__ __forceinline__ void conv_row_acc2(f2* a, float4 mid, float lf, float rt,
    const float* wp0, const float* wp1){
  f2 w0 = mkf2(wp0[0],wp1[0]);
  f2 w1 = mkf2(wp0[1],wp1[1]);
  f2 w2 = mkf2(wp0[2],wp1[2]);
  a[0] = fma2(w0,lf,   fma2(w1,mid.x, fma2(w2,mid.y, a[0])));
  a[1] = fma2(w0,mid.x,fma2(w1,mid.y, fma2(w2,mid.z, a[1])));
  a[2] = fma2(w0,mid.y,fma2(w1,mid.z, fma2(w2,mid.w, a[2])));
  a[3] = fma2(w0,mid.z,fma2(w1,mid.w, fma2(w2,rt,    a[3])));
}

__device__ __forceinline__ void conv_ci_body2(float4 m0, float4 m1, float4 m2, int q,
    const float* wp0, const float* wp1, f2* a){
  float lf0=__shfl_up(m0.w,1,64), rt0=__shfl_down(m0.x,1,64);
  float lf1=__shfl_up(m1.w,1,64), rt1=__shfl_down(m1.x,1,64);
  float lf2=__shfl_up(m2.w,1,64), rt2=__shfl_down(m2.x,1,64);
  if (q==0){ lf0=0.f; lf1=0.f; lf2=0.f; }
  if (q==7){ rt0=0.f; rt1=0.f; rt2=0.f; }
  conv_row_acc2(a,m0,lf0,rt0, wp0+0, wp1+0);
  conv_row_acc2(a,m1,lf1,rt1, wp0+3, wp1+3);
  conv_row_acc2(a,m2,lf2,rt2, wp0+6, wp1+6);
}

// ---------------- k3: conv1 192ci->64co, split-K=12 (16 ci each), 2304 blocks
__global__ __launch_bounds__(256) void k_conv1_split(const float* __restrict__ xact,
    const float* __restrict__ w, float* __restrict__ part){
  int bx = blockIdx.x; int kk = bx % 12; int r = bx / 12;
  int cop = r & 31; int s = r >> 5;
  int co0 = cop*2, co1 = co0+1;
  int tid = threadIdx.x; int row = tid>>3; int q = tid&7; int col0 = q*4;
  f2 a[4];
  #pragma unroll
  for (int i=0;i<4;++i){ a[i].x=0.f; a[i].y=0.f; }
  int ci0 = kk*16;
  const float* pl = xact + ((size_t)s*C3 + ci0)*PSTR + row*32 + col0;
  const float* wp0 = w + (size_t)(co0*C3 + ci0)*9;
  const float* wp1 = w + (size_t)(co1*C3 + ci0)*9;
  float4 m0 = *(const float4*)(pl);
  float4 m1 = *(const float4*)(pl+32);
  float4 m2 = *(const float4*)(pl+64);
  #pragma unroll 2
  for (int i=0;i<16;++i){
    const float* pn = pl + (i<15 ? PSTR : 0);
    float4 n0 = *(const float4*)(pn);
    float4 n1 = *(const float4*)(pn+32);
    float4 n2 = *(const float4*)(pn+64);
    conv_ci_body2(m0,m1,m2,q, wp0, wp1, a);
    wp0 += 9; wp1 += 9; pl = pn; m0=n0; m1=n1; m2=n2;
  }
  float* pp = part + (size_t)kk*(BL*CCH*L2) + ((size_t)s*CCH+co0)*L2 + row*32+col0;
  *(float4*)pp = make_float4(a[0].x,a[1].x,a[2].x,a[3].x);
  *(float4*)(pp+L2) = make_float4(a[0].y,a[1].y,a[2].y,a[3].y);
}

// ---------------- k4: reduce conv1 partials (12) + bias -> h1; GN2 partials
__global__ __launch_bounds__(256) void k_reduce1(const float* __restrict__ part,
    const float* __restrict__ bias, float* __restrict__ h1,
    float* __restrict__ psum2, float* __restrict__ psq2){
  int co = blockIdx.x & 63; int s = blockIdx.x >> 6;
  size_t ofs = ((size_t)s*CCH+co)*L2 + threadIdx.x*4;
  const size_t stride = (size_t)BL*CCH*L2;
  float4 acc = *(const float4*)(part + ofs);
  #pragma unroll
  for (int kk=1;kk<12;++kk){
    float4 r = *(const float4*)(part + (size_t)kk*stride + ofs);
    acc.x += r.x; acc.y += r.y; acc.z += r.z; acc.w += r.w;
  }
  float bv = bias[co];
  acc.x += bv; acc.y += bv; acc.z += bv; acc.w += bv;
  *(float4*)(h1 + ofs) = acc;
  float sm = acc.x+acc.y+acc.z+acc.w;
  float sq = acc.x*acc.x+acc.y*acc.y+acc.z*acc.z+acc.w*acc.w;
  for (int m=1;m<64;m<<=1){ sm+=__shfl_xor(sm,m,64); sq+=__shfl_xor(sq,m,64); }
  __shared__ float s_sm[4], s_sq[4];
  int wv = threadIdx.x>>6;
  if ((threadIdx.x&63)==0){ s_sm[wv]=sm; s_sq[wv]=sq; }
  __syncthreads();
  if (threadIdx.x==0){
    psum2[blockIdx.x] = s_sm[0]+s_sm[1]+s_sm[2]+s_sm[3];
    psq2 [blockIdx.x] = s_sq[0]+s_sq[1]+s_sq[2]+s_sq[3];
  }
}

// ---------------- k6: conv2 FOUR roles x 16ci, 768 blocks
__global__ __launch_bounds__(256) void k_conv2_split(const float* __restrict__ xact2,
    const float* __restrict__ w2, float* __restrict__ part){
  int bx = blockIdx.x; int role = bx & 3; int t = bx >> 2;
  int cop = t & 31; int s = t >> 5;
  int co0 = cop*2, co1 = co0+1;
  int tid = threadIdx.x; int row = tid>>3; int q = tid&7; int col0 = q*4;
  int p = row*32+col0;
  f2 a[4];
  #pragma unroll
  for (int i=0;i<4;++i){ a[i].x=0.f; a[i].y=0.f; }
  int ci0 = role*16;
  const float* pl = xact2 + ((size_t)s*CCH + ci0)*PSTR + row*32 + col0;
  const float* wp0 = w2 + (size_t)(co0*CCH + ci0)*9;
  const float* wp1 = w2 + (size_t)(co1*CCH + ci0)*9;
  float4 m0 = *(const float4*)(pl);
  float4 m1 = *(const float4*)(pl+32);
  float4 m2 = *(const float4*)(pl+64);
  #pragma unroll 2
  for (int i=0;i<16;++i){
    const float* pn = pl + (i<15 ? PSTR : 0);
    float4 n0 = *(const float4*)(pn);
    float4 n1 = *(const float4*)(pn+32);
    float4 n2 = *(const float4*)(pn+64);
    conv_ci_body2(m0,m1,m2,q, wp0, wp1, a);
    wp0 += 9; wp1 += 9; pl = pn; m0=n0; m1=n1; m2=n2;
  }
  float* pp = part + (size_t)role*(BL*CCH*L2) + ((size_t)s*CCH+co0)*L2 + p;
  *(float4*)pp = make_float4(a[0].x,a[1].x,a[2].x,a[3].x);
  *(float4*)(pp+L2) = make_float4(a[0].y,a[1].y,a[2].y,a[3].y);
}

// ---------------- k7: reduce2(6 slots) + ln1 + in_proj fused, oq split x16, 1536 blocks
__global__ __launch_bounds__(256) void k_red2_ln1_inproj(const float* __restrict__ part,
    const float* __restrict__ b2, const float* __restrict__ bsk,
    const float* __restrict__ g, const float* __restrict__ b,
    const float* __restrict__ W,
    float* __restrict__ x_cmaj, float* __restrict__ xc, float* __restrict__ z_t){
  __shared__ float xn_s[64*65];
  int bx = blockIdx.x; int oq = bx & 15; int pg = (bx>>4)&15; int s = bx>>8;
  int p0 = pg*64;
  int tid = threadIdx.x;
  const size_t stride = (size_t)BL*CCH*L2;
  #pragma unroll
  for (int kq=0;kq<4;++kq){
    int f = kq*256 + tid;
    int co = f >> 4; int px4 = (f & 15)*4;
    size_t ofs = ((size_t)s*CCH+co)*L2 + p0 + px4;
    float4 r0 = *(const float4*)(part + ofs);
    float4 r1 = *(const float4*)(part + stride + ofs);
    float4 r2 = *(const float4*)(part + 2*stride + ofs);
    float4 r3 = *(const float4*)(part + 3*stride + ofs);
    float4 r4 = *(const float4*)(part + 4*stride + ofs);
    float4 r5 = *(const float4*)(part + 5*stride + ofs);
    float bv = b2[co]+bsk[co];
    float4 o;
    o.x = ((r0.x+r1.x)+(r2.x+r3.x))+(r4.x+r5.x)+bv;
    o.y = ((r0.y+r1.y)+(r2.y+r3.y))+(r4.y+r5.y)+bv;
    o.z = ((r0.z+r1.z)+(r2.z+r3.z))+(r4.z+r5.z)+bv;
    o.w = ((r0.w+r1.w)+(r2.w+r3.w))+(r4.w+r5.w)+bv;
    if (oq == 0) *(float4*)(x_cmaj + ofs) = o;
    xn_s[(px4+0)*65 + co] = o.x;
    xn_s[(px4+1)*65 + co] = o.y;
    xn_s[(px4+2)*65 + co] = o.z;
    xn_s[(px4+3)*65 + co] = o.w;
  }
  __syncthreads();
  {
    int wv = __builtin_amdgcn_readfirstlane(tid>>6); int lane = tid&63;
    for (int j=0;j<16;++j){
      int pl = wv*16 + j;
      float v = xn_s[pl*65 + lane];
      float sm = v, sq = v*v;
      for (int m=1;m<64;m<<=1){ sm += __shfl_xor(sm,m,64); sq += __shfl_xor(sq,m,64); }
      float mean = sm*(1.f/64.f); float var = sq*(1.f/64.f) - mean*mean;
      float rs = rsqrtf(var + 1e-5f);
      xn_s[pl*65 + lane] = (v-mean)*rs*g[lane] + b[lane];
    }
  }
  __syncthreads();
  int px_l = tid & 63;
  int og = __builtin_amdgcn_readfirstlane(tid >> 6);
  int o0 = oq*16 + og*4;
  f2 acc[2];
  acc[0].x=0.f; acc[0].y=0.f; acc[1].x=0.f; acc[1].y=0.f;
  for (int c=0;c<64;++c){
    float xv = xn_s[px_l*65 + c];
    acc[0] = fma2(mkf2(W[(o0+0)*64 + c], W[(o0+1)*64 + c]), xv, acc[0]);
    acc[1] = fma2(mkf2(W[(o0+2)*64 + c], W[(o0+3)*64 + c]), xv, acc[1]);
  }
  int p = p0 + px_l;
  if (oq < 8){
    xc[((size_t)s*DIC + o0+0)*L2 + p] = acc[0].x;
    xc[((size_t)s*DIC + o0+1)*L2 + p] = acc[0].y;
    xc[((size_t)s*DIC + o0+2)*L2 + p] = acc[1].x;
    xc[((size_t)s*DIC + o0+3)*L2 + p] = acc[1].y;
  } else {
    int oz = o0 - 128;
    z_t[((size_t)s*DIC + oz+0)*L2 + p] = acc[0].x;
    z_t[((size_t)s*DIC + oz+1)*L2 + p] = acc[0].y;
    z_t[((size_t)s*DIC + oz+2)*L2 + p] = acc[1].x;
    z_t[((size_t)s*DIC + oz+3)*L2 + p] = acc[1].y;
  }
}

// ---------------- k8: x_proj + INLINE depthwise 3x3 + SiLU — HALF-SPLIT, 768 blocks
__global__ __launch_bounds__(256) void k_xproj_dt(const float* __restrict__ xc,
    const float* __restrict__ dww, const float* __restrict__ dwb,
    const float* __restrict__ W,
    float* __restrict__ dtr, float* __restrict__ Bp, float* __restrict__ Cp,
    float* __restrict__ u_t){
  __shared__ float smem[128*68];
  int bx = blockIdx.x; int half = bx & 1; int pg = (bx>>1) & 15; int sk = bx >> 5;
  int k = sk & 3; int s = sk >> 2;
  int tid = threadIdx.x;
  for (int i = tid; i < 128*16; i += 256){
    int dr = i>>4; int j4 = (i&15)*4;
    int rw = j4>>5; int col0 = j4 & 31;
    int gr = pg*2 + rw;
    int q = i&7;
    const float* xr = xc + ((size_t)s*DIC+dr)*L2;
    const float* wp = dww + dr*9;
    float bv = dwb[dr];
    float4 acc = make_float4(bv,bv,bv,bv);
    #pragma unroll
    for (int dy=-1;dy<=1;++dy){
      int r = gr+dy;
      float4 mid = make_float4(0.f,0.f,0.f,0.f);
      if (0<=r && r<32) mid = *(const float4*)(xr + r*32 + col0);
      float lf = __shfl_up(mid.w,1,64); if(q==0) lf=0.f;
      float rt = __shfl_down(mid.x,1,64); if(q==7) rt=0.f;
      float w0=wp[(dy+1)*3], w1=wp[(dy+1)*3+1], w2=wp[(dy+1)*3+2];
      acc.x = fmaf(w0,lf,   fmaf(w1,mid.x, fmaf(w2,mid.y, acc.x)));
      acc.y = fmaf(w0,mid.x,fmaf(w1,mid.y, fmaf(w2,mid.z, acc.y)));
      acc.z = fmaf(w0,mid.y,fmaf(w1,mid.z, fmaf(w2,mid.w, acc.z)));
      acc.w = fmaf(w0,mid.z,fmaf(w1,mid.w, fmaf(w2,rt,    acc.w)));
    }
    acc.x = fsilu(acc.x); acc.y = fsilu(acc.y); acc.z = fsilu(acc.z); acc.w = fsilu(acc.w);
    *(float4*)&smem[dr*68 + j4] = acc;
  }
  __syncthreads();
  int px = tid & 63;
  int cgrp = __builtin_amdgcn_readfirstlane(tid >> 6);
  if (half == 1){
    if (k == 0){
      float* ub = u_t + ((size_t)(s*L2) + pg*64)*DIC;
      for (int i = tid; i < 64*128; i += 256){
        int px2 = i>>7; int dd = i&127;
        ub[(size_t)px2*DIC + dd] = smem[dd*68 + px2];
      }
    }
    int c0 = 20 + cgrp*4;
    const float* wb = W + (size_t)(k*36 + c0)*DIC;
    f2 acc2[2];
    acc2[0].x=0.f; acc2[0].y=0.f; acc2[1].x=0.f; acc2[1].y=0.f;
    for (int d=0; d<DIC; ++d){
      float xv = smem[d*68 + px];
      acc2[0] = fma2(mkf2(wb[0*DIC+d], wb[1*DIC+d]), xv, acc2[0]);
      acc2[1] = fma2(mkf2(wb[2*DIC+d], wb[3*DIC+d]), xv, acc2[1]);
    }
    __syncthreads();
    smem[(c0+0)*68 + px] = acc2[0].x;
    smem[(c0+1)*68 + px] = acc2[0].y;
    smem[(c0+2)*68 + px] = acc2[1].x;
    smem[(c0+3)*68 + px] = acc2[1].y;
    __syncthreads();
    float* Cb = Cp + ((size_t)sk*L2 + pg*64)*NST;
    for (int i = tid; i < 1024; i += 256){
      int pp = i>>4; int n = i&15;
      Cb[pp*NST + n] = smem[(20+n)*68 + pp];
    }
  } else {
    int c0 = cgrp*5;
    const float* wb = W + (size_t)(k*36 + c0)*DIC;
    f2 acc2[2]; float acc4 = 0.f;
    acc2[0].x=0.f; acc2[0].y=0.f; acc2[1].x=0.f; acc2[1].y=0.f;
    for (int d=0; d<DIC; ++d){
      float xv = smem[d*68 + px];
      acc2[0] = fma2(mkf2(wb[0*DIC+d], wb[1*DIC+d]), xv, acc2[0]);
      acc2[1] = fma2(mkf2(wb[2*DIC+d], wb[3*DIC+d]), xv, acc2[1]);
      acc4 = fmaf(wb[4*DIC+d], xv, acc4);
    }
    __syncthreads();
    smem[(c0+0)*68 + px] = acc2[0].x;
    smem[(c0+1)*68 + px] = acc2[0].y;
    smem[(c0+2)*68 + px] = acc2[1].x;
    smem[(c0+3)*68 + px] = acc2[1].y;
    smem[(c0+4)*68 + px] = acc4;
    __syncthreads();
    {
      int pp = tid >> 2; int r = tid & 3;
      dtr[((size_t)sk*L2 + pg*64 + pp)*4 + r] = smem[r*68 + pp];
    }
    float* Bb = Bp + ((size_t)sk*L2 + pg*64)*NST;
    for (int i = tid; i < 1024; i += 256){
      int pp = i>>4; int n = i&15;
      Bb[pp*NST + n] = smem[(4+n)*68 + pp];
    }
  }
}

// scan pixel for direction k, chunk ch (32 steps), step j
__device__ __forceinline__ int scan_pix32(int ch, int j, int k){
  if (k==0) return ch*32 + j;
  if (k==1) return j*32 + ch;
  if (k==2) return 1023 - (ch*32 + j);
  return 1023 - (j*32 + ch);
}

// half-state step (8 of 16 SSM states per thread)
struct StepH { float4 dt4; float uv; float4 B0,B1; };
__device__ __forceinline__ StepH loadH(const float* dr, const float* ub, const float* Bb, int p){
  StepH r;
  r.dt4 = *(const float4*)(dr + (size_t)p*4);
  r.uv = ub[(size_t)p*DIC];
  const float* bp = Bb + p*NST;   // Bb pre-offset by nh*8
  r.B0 = *(const float4*)bp; r.B1 = *(const float4*)(bp+4);
  return r;
}
__device__ __forceinline__ float dt_eval(float4 w4, float bb, float4 d4){
  return fsoftplus(fmaf(w4.x,d4.x,fmaf(w4.y,d4.y,fmaf(w4.z,d4.z,fmaf(w4.w,d4.w,bb)))));
}

// check: aco[n] == (gbase+n+1)*acoR for all local n (A = -(n+1) structure)
__device__ __forceinline__ bool aco_linear(const float* aco, float acoR, int gbase){
  bool ok = true;
  #pragma unroll
  for (int n=0;n<8;++n){
    float ideal = (float)(gbase+n+1) * acoR;
    ok = ok && (fabsf(aco[n]-ideal) <= 1e-5f*fabsf(ideal) + 1e-12f);
  }
  return ok;
}

// ---------------- k9: scan pass 1, n-split, 768 blocks (R9-proven body)
__global__ __launch_bounds__(256,4) void k_scan_part3(const float* __restrict__ dtr,
    const float* __restrict__ dtw, const float* __restrict__ dtb,
    const float* __restrict__ u_t, const float* __restrict__ Bp,
    const float* __restrict__ A_logs, float* __restrict__ hend, float* __restrict__ Ssum){
  int bx = blockIdx.x; int ch = bx & 31; int sk = bx >> 5;
  int k = sk & 3; int s = sk >> 2;
  int tid = threadIdx.x; int d = tid >> 1; int nh = tid & 1;
  float aco[8];
  float acoR = -LOG2E * fexp(A_logs[(size_t)(k*DIC+d)*NST]);
  {
    const float* ab = A_logs + (size_t)(k*DIC+d)*NST + nh*8;
    #pragma unroll
    for (int n=0;n<8;++n) aco[n] = -LOG2E * fexp(ab[n]);
  }
  bool fast = aco_linear(aco, acoR, nh*8);
  float aco0 = aco[0];
  float4 w4 = *(const float4*)(dtw + (size_t)(k*DIC+d)*4);
  float bb = dtb[k*DIC+d];
  float h[8]; float Sacc = 0.f;
  #pragma unroll
  for (int n=0;n<8;++n) h[n]=0.f;
  const float* dr = dtr + (size_t)sk*L2*4;
  const float* ub = u_t + (size_t)s*L2*DIC + d;
  const float* Bb = Bp + (size_t)sk*L2*NST + nh*8;
  StepH cur = loadH(dr, ub, Bb, scan_pix32(ch, 0, k));
  if (fast){
    #pragma unroll 4
    for (int j=0;j<32;++j){
      StepH nxt;
      if (j < 31) nxt = loadH(dr, ub, Bb, scan_pix32(ch, j+1, k));
      float dtv = dt_eval(w4, bb, cur.dt4);
      Sacc += dtv;
      float tv = dtv*cur.uv;
      float rr = __builtin_amdgcn_exp2f(dtv*acoR);
      float a_ = __builtin_amdgcn_exp2f(dtv*aco0);
      h[0] = fmaf(a_, h[0], tv*cur.B0.x);
      a_ *= rr; h[1] = fmaf(a_, h[1], tv*cur.B0.y);
      a_ *= rr; h[2] = fmaf(a_, h[2], tv*cur.B0.z);
      a_ *= rr; h[3] = fmaf(a_, h[3], tv*cur.B0.w);
      a_ *= rr; h[4] = fmaf(a_, h[4], tv*cur.B1.x);
      a_ *= rr; h[5] = fmaf(a_, h[5], tv*cur.B1.y);
      a_ *= rr; h[6] = fmaf(a_, h[6], tv*cur.B1.z);
      a_ *= rr; h[7] = fmaf(a_, h[7], tv*cur.B1.w);
      cur = nxt;
    }
  } else {
    #pragma unroll 4
    for (int j=0;j<32;++j){
      StepH nxt;
      if (j < 31) nxt = loadH(dr, ub, Bb, scan_pix32(ch, j+1, k));
      float dtv = dt_eval(w4, bb, cur.dt4);
      Sacc += dtv;
      float tv = dtv*cur.uv;
      #define PSTEP(NI, BV) { float a_ = __builtin_amdgcn_exp2f(dtv*aco[NI]); \
        h[NI] = fmaf(a_, h[NI], tv*(BV)); }
      PSTEP(0,cur.B0.x) PSTEP(1,cur.B0.y) PSTEP(2,cur.B0.z) PSTEP(3,cur.B0.w)
      PSTEP(4,cur.B1.x) PSTEP(5,cur.B1.y) PSTEP(6,cur.B1.z) PSTEP(7,cur.B1.w)
      #undef PSTEP
      cur = nxt;
    }
  }
  size_t base = ((size_t)(sk*NCH + ch)*DIC + d)*NST + nh*8;
  *(float4*)(hend + base)     = make_float4(h[0],h[1],h[2],h[3]);
  *(float4*)(hend + base + 4) = make_float4(h[4],h[5],h[6],h[7]);
  if (nh == 0) Ssum[(size_t)(sk*NCH + ch)*DIC + d] = Sacc;
}

// ---------------- k10: full scan + y output, n-split, 768 blocks (R9-proven body)
__global__ __launch_bounds__(256,4) void k_scan_y3(const float* __restrict__ dtr,
    const float* __restrict__ dtw, const float* __restrict__ dtb,
    const float* __restrict__ u_t, const float* __restrict__ Bp, const float* __restrict__ Cp,
    const float* __restrict__ A_logs, const float* __restrict__ Ds,
    const float* __restrict__ hend, const float* __restrict__ Ssum,
    float* __restrict__ ys_t){
  int bx = blockIdx.x; int ch = bx & 31; int sk = bx >> 5;
  int k = sk & 3; int s = sk >> 2;
  int tid = threadIdx.x; int d = tid >> 1; int nh = tid & 1;
  float aco[8];
  float acoR = -LOG2E * fexp(A_logs[(size_t)(k*DIC+d)*NST]);
  {
    const float* ab = A_logs + (size_t)(k*DIC+d)*NST + nh*8;
    #pragma unroll
    for (int n=0;n<8;++n) aco[n] = -LOG2E * fexp(ab[n]);
  }
  bool fast = aco_linear(aco, acoR, nh*8);
  float aco0 = aco[0];
  float4 w4 = *(const float4*)(dtw + (size_t)(k*DIC+d)*4);
  float bb = dtb[k*DIC+d];
  float Dv = Ds[k*DIC+d];
  // inline chunk-prefix over chunks 0..ch-1
  float h[8];
  #pragma unroll
  for (int n=0;n<8;++n) h[n]=0.f;
  {
    const float* Sb = Ssum + (size_t)sk*NCH*DIC + d;
    const float* Hb = hend + ((size_t)sk*NCH*DIC + d)*NST + nh*8;
    for (int cc=0; cc<ch; ++cc){
      float Sv = Sb[(size_t)cc*DIC];
      float4 e0 = *(const float4*)(Hb + (size_t)cc*DIC*NST);
      float4 e1 = *(const float4*)(Hb + (size_t)cc*DIC*NST + 4);
      if (fast){
        float rr = __builtin_amdgcn_exp2f(acoR*Sv);
        float a_ = __builtin_amdgcn_exp2f(aco0*Sv);
        h[0] = fmaf(a_, h[0], e0.x);
        a_ *= rr; h[1] = fmaf(a_, h[1], e0.y);
        a_ *= rr; h[2] = fmaf(a_, h[2], e0.z);
        a_ *= rr; h[3] = fmaf(a_, h[3], e0.w);
        a_ *= rr; h[4] = fmaf(a_, h[4], e1.x);
        a_ *= rr; h[5] = fmaf(a_, h[5], e1.y);
        a_ *= rr; h[6] = fmaf(a_, h[6], e1.z);
        a_ *= rr; h[7] = fmaf(a_, h[7], e1.w);
      } else {
        float he[8] = {e0.x,e0.y,e0.z,e0.w,e1.x,e1.y,e1.z,e1.w};
        #pragma unroll
        for (int n=0;n<8;++n){
          float pa = __builtin_amdgcn_exp2f(aco[n]*Sv);
          h[n] = fmaf(pa, h[n], he[n]);
        }
      }
    }
  }
  const float* dr = dtr + (size_t)sk*L2*4;
  const float* ub = u_t + (size_t)s*L2*DIC + d;
  const float* Bb = Bp + (size_t)sk*L2*NST + nh*8;
  const float* Cb = Cp + (size_t)sk*L2*NST + nh*8;
  float* yb = ys_t + (size_t)sk*L2*DIC + d;
  int pcur = scan_pix32(ch, 0, k);
  StepH cur = loadH(dr, ub, Bb, pcur);
  float4 Cc0 = *(const float4*)(Cb + pcur*NST);
  float4 Cc1 = *(const float4*)(Cb + pcur*NST + 4);
  if (fast){
    #pragma unroll 4
    for (int j=0;j<32;++j){
      StepH nxt; float4 Cn0, Cn1; int pn = pcur;
      if (j < 31){
        pn = scan_pix32(ch, j+1, k);
        nxt = loadH(dr, ub, Bb, pn);
        Cn0 = *(const float4*)(Cb + pn*NST);
        Cn1 = *(const float4*)(Cb + pn*NST + 4);
      }
      float dtv = dt_eval(w4, bb, cur.dt4);
      float tv = dtv*cur.uv;
      float y0=0.f, y1=0.f, y2=0.f, y3=0.f;
      float rr = __builtin_amdgcn_exp2f(dtv*acoR);
      float a_ = __builtin_amdgcn_exp2f(dtv*aco0);
      h[0] = fmaf(a_, h[0], tv*cur.B0.x); y0 = fmaf(h[0], Cc0.x, y0);
      a_ *= rr; h[1] = fmaf(a_, h[1], tv*cur.B0.y); y1 = fmaf(h[1], Cc0.y, y1);
      a_ *= rr; h[2] = fmaf(a_, h[2], tv*cur.B0.z); y2 = fmaf(h[2], Cc0.z, y2);
      a_ *= rr; h[3] = fmaf(a_, h[3], tv*cur.B0.w); y3 = fmaf(h[3], Cc0.w, y3);
      a_ *= rr; h[4] = fmaf(a_, h[4], tv*cur.B1.x); y0 = fmaf(h[4], Cc1.x, y0);
      a_ *= rr; h[5] = fmaf(a_, h[5], tv*cur.B1.y); y1 = fmaf(h[5], Cc1.y, y1);
      a_ *= rr; h[6] = fmaf(a_, h[6], tv*cur.B1.z); y2 = fmaf(h[6], Cc1.z, y2);
      a_ *= rr; h[7] = fmaf(a_, h[7], tv*cur.B1.w); y3 = fmaf(h[7], Cc1.w, y3);
      float py = (y0+y1)+(y2+y3);
      float tot = py + __shfl_xor(py, 1, 64);
      if (nh == 0) yb[(size_t)pcur*DIC] = fmaf(cur.uv, Dv, tot);
      cur = nxt; Cc0 = Cn0; Cc1 = Cn1; pcur = pn;
    }
  } else {
    #pragma unroll 4
    for (int j=0;j<32;++j){
      StepH nxt; float4 Cn0, Cn1; int pn = pcur;
      if (j < 31){
        pn = scan_pix32(ch, j+1, k);
        nxt = loadH(dr, ub, Bb, pn);
        Cn0 = *(const float4*)(Cb + pn*NST);
        Cn1 = *(const float4*)(Cb + pn*NST + 4);
      }
      float dtv = dt_eval(w4, bb, cur.dt4);
      float tv = dtv*cur.uv;
      float y0=0.f, y1=0.f, y2=0.f, y3=0.f;
      #define YSTEP(NI, BV, CV, YA) { float a_ = __builtin_amdgcn_exp2f(dtv*aco[NI]); \
        h[NI] = fmaf(a_, h[NI], tv*(BV)); YA = fmaf(h[NI], (CV), YA); }
      YSTEP(0,cur.B0.x,Cc0.x,y0) YSTEP(1,cur.B0.y,Cc0.y,y1) YSTEP(2,cur.B0.z,Cc0.z,y2) YSTEP(3,cur.B0.w,Cc0.w,y3)
      YSTEP(4,cur.B1.x,Cc1.x,y0) YSTEP(5,cur.B1.y,Cc1.y,y1) YSTEP(6,cur.B1.z,Cc1.z,y2) YSTEP(7,cur.B1.w,Cc1.w,y3)
      #undef YSTEP
      float py = (y0+y1)+(y2+y3);
      float tot = py + __shfl_xor(py, 1, 64);
      if (nh == 0) yb[(size_t)pcur*DIC] = fmaf(cur.uv, Dv, tot);
      cur = nxt; Cc0 = Cn0; Cc1 = Cn1; pcur = pn;
    }
  }
}

// ---------------- k11: fused tail, 4 px per block, 1536 blocks
__global__ __launch_bounds__(256) void k_tail(const float* __restrict__ ys_t,
    const float* __restrict__ z_t, const float* __restrict__ ong, const float* __restrict__ onb,
    const float* __restrict__ Wop, const float* __restrict__ x_cmaj,
    const float* __restrict__ g2, const float* __restrict__ b2n,
    const float* __restrict__ w1, const float* __restrict__ b1,
    const float* __restrict__ w2, const float* __restrict__ b2,
    float* __restrict__ out){
  __shared__ float yt[128*5];
  __shared__ float xvt[64*5];
  __shared__ float ts[64*5];
  int s = blockIdx.x >> 8; int pg = blockIdx.x & 255;
  int tid = threadIdx.x;
  {
    int wv = __builtin_amdgcn_readfirstlane(tid>>6); int lane = tid&63;
    int d0 = lane, d1 = lane+64;
    int px = wv; int p = pg*4 + px;
    const float* yb = ys_t + ((size_t)(s*4)*L2 + p)*DIC;
    float ya = yb[d0] + yb[(size_t)L2*DIC + d0] + yb[(size_t)2*L2*DIC + d0] + yb[(size_t)3*L2*DIC + d0];
    float yc = yb[d1] + yb[(size_t)L2*DIC + d1] + yb[(size_t)2*L2*DIC + d1] + yb[(size_t)3*L2*DIC + d1];
    float sm = ya+yc, sq = ya*ya+yc*yc;
    for (int m=1;m<64;m<<=1){ sm+=__shfl_xor(sm,m,64); sq+=__shfl_xor(sq,m,64); }
    float mean = sm*(1.f/128.f); float var = sq*(1.f/128.f)-mean*mean;
    float rs = rsqrtf(var + 1e-5f);
    float yn0 = (ya-mean)*rs*ong[d0] + onb[d0];
    float yn1 = (yc-mean)*rs*ong[d1] + onb[d1];
    float zv0 = z_t[((size_t)s*DIC+d0)*L2 + p];
    float zv1 = z_t[((size_t)s*DIC+d1)*L2 + p];
    yt[d0*5 + px] = yn0 * fsilu(zv0);
    yt[d1*5 + px] = yn1 * fsilu(zv1);
  }
  __syncthreads();
  {
    int px = tid & 3; int c0 = tid >> 2;
    float A = 0.f;
    for (int d=0; d<DIC; ++d)
      A = fmaf(Wop[c0*DIC + d], yt[d*5 + px], A);
    int p = pg*4 + px;
    xvt[c0*5 + px] = x_cmaj[((size_t)s*CCH + c0)*L2 + p] + A;
  }
  __syncthreads();
  int px = tid & 3; int cgp = tid >> 2;
  float sm=0.f, sq=0.f;
  for (int c=0;c<64;++c){ float v = xvt[c*5+px]; sm+=v; sq+=v*v; }
  float mean = sm*(1.f/64.f);
  float rs = rsqrtf(sq*(1.f/64.f) - mean*mean + 1e-5f);
  float T = b1[cgp];
  for (int c=0;c<64;++c){
    float xn = (xvt[c*5+px]-mean)*rs*g2[c] + b2n[c];
    T = fmaf(xn, w1[cgp*64 + c], T);
  }
  ts[cgp*5 + px] = fgelu(T);
  __syncthreads();
  float ACC = xvt[cgp*5+px] + b2[cgp];
  for (int o=0;o<64;++o)
    ACC = fmaf(ts[o*5+px], w2[cgp*64 + o], ACC);
  int p = pg*4 + px;
  out[((size_t)s*CCH + cgp)*L2 + p] = ACC;
}

extern "C" void kernel_launch(void* const* d_in, const int* in_sizes, int n_in,
                              void* d_out, int out_size, void* d_ws, size_t ws_size,
                              hipStream_t stream){
  (void)in_sizes; (void)n_in; (void)out_size; (void)ws_size;
  const float* img      = (const float*)d_in[0];
  const float* dz       = (const float*)d_in[1];
  const float* sg       = (const float*)d_in[2];
  const float* norm_g   = (const float*)d_in[3];
  const float* norm_b   = (const float*)d_in[4];
  const float* gn1_g    = (const float*)d_in[5];
  const float* gn1_b    = (const float*)d_in[6];
  const float* conv1_w  = (const float*)d_in[7];
  const float* conv1_b  = (const float*)d_in[8];
  const float* gn2_g    = (const float*)d_in[9];
  const float* gn2_b    = (const float*)d_in[10];
  const float* conv2_w  = (const float*)d_in[11];
  const float* conv2_b  = (const float*)d_in[12];
  const float* skip_w   = (const float*)d_in[13];
  const float* skip_b   = (const float*)d_in[14];
  const float* ln1_g    = (const float*)d_in[15];
  const float* ln1_b    = (const float*)d_in[16];
  const float* ln2_g    = (const float*)d_in[17];
  const float* ln2_b    = (const float*)d_in[18];
  const float* in_proj_w= (const float*)d_in[19];
  const float* dwconv_w = (const float*)d_in[20];
  const float* dwconv_b = (const float*)d_in[21];
  const float* x_proj_w = (const float*)d_in[22];
  const float* dt_proj_w= (const float*)d_in[23];
  const float* dt_proj_b= (const float*)d_in[24];
  const float* A_logs   = (const float*)d_in[25];
  const float* Ds       = (const float*)d_in[26];
  const float* out_norm_g = (const float*)d_in[27];
  const float* out_norm_b = (const float*)d_in[28];
  const float* out_proj_w = (const float*)d_in[29];
  const float* fc1_w    = (const float*)d_in[30];
  const float* fc1_b    = (const float*)d_in[31];
  const float* fc2_w    = (const float*)d_in[32];
  const float* fc2_b    = (const float*)d_in[33];

  float* ws = (float*)d_ws;
  float* x3c    = ws;                       // 1,179,648
  float* xact1  = x3c    + 1179648;         // 1,253,376 (padded GN1 act)
  float* h1     = xact1  + 1253376;         // 393,216
  float* xact2  = h1     + 393216;          // 417,792 (padded GN2 act)
  float* xpslot = xact2  + 417792;          // 393,216 (hosts Bp)
  float* x_cmaj = xpslot + 393216;          // 393,216
  float* z_t    = x_cmaj + 393216;          // 786,432
  float* xc     = z_t    + 786432;          // 786,432
  float* cpslot = xc     + 786432;          // 786,432 (hosts Cp)
  float* hole   = cpslot + 786432;          // 884,736 (dtr + Ssum)
  float* scanbuf= hole   + 884736;          // 3,145,728 (conv1 partials)
  float* ys_t   = scanbuf+ 3145728;         // 3,145,728 (conv2 partials + skip first)
  float* statsb = ys_t   + 3145728;         // psum1(1536) psq1(1536) psum2(384) psq2(384)
  float* psum1  = statsb;
  float* psq1   = statsb + 1536;
  float* psum2  = statsb + 3072;
  float* psq2   = statsb + 3456;
  // aliases into dead regions (timeline-verified, same as R7-R9):
  float* part1  = scanbuf;          // conv1 partials (12 slots: scanbuf + ys_t[0..4))
  float* part2  = ys_t;             // conv2 partials slots 0-3; skip slots 4,5
  float* hend   = x3c;              // x3c+xact1 dead after k_gnact1_skip/conv1
  float* u_t    = h1;               // h1+xact2 dead after gnact2/conv2
  float* Bp     = xpslot;
  float* Cp     = cpslot;
  float* dtr    = hole;             // 98,304
  float* Ssum   = hole + 98304;     // 98,304

  k_ln2d<<<1536, 256, 0, stream>>>(img, dz, sg, norm_g, norm_b, x3c, psum1, psq1);
  k_gnact1_skip<<<1536, 256, 0, stream>>>(x3c, psum1, psq1, gn1_g, gn1_b, skip_w,
                                          xact1, part2);
  k_conv1_split<<<2304, 256, 0, stream>>>(xact1, conv1_w, part1);
  k_reduce1<<<384, 256, 0, stream>>>(part1, conv1_b, h1, psum2, psq2);
  k_gnact_pad<<<2*6*CCH, 256, 0, stream>>>(h1, psum2, psq2, gn2_g, gn2_b, CCH, 64,
                                           1.f/(CCH*L2), 1e-5f, xact2);
  k_conv2_split<<<768, 256, 0, stream>>>(xact2, conv2_w, part2);
  k_red2_ln1_inproj<<<1536, 256, 0, stream>>>(part2, conv2_b, skip_b, ln1_g, ln1_b, in_proj_w,
                                              x_cmaj, xc, z_t);
  k_xproj_dt<<<768, 256, 0, stream>>>(xc, dwconv_w, dwconv_b, x_proj_w, dtr, Bp, Cp, u_t);
  k_scan_part3<<<768, 256, 0, stream>>>(dtr, dt_proj_w, dt_proj_b, u_t, Bp, A_logs, hend, Ssum);
  k_scan_y3<<<768, 256, 0, stream>>>(dtr, dt_proj_w, dt_proj_b, u_t, Bp, Cp, A_logs, Ds,
                                     hend, Ssum, ys_t);
  k_tail<<<1536, 256, 0, stream>>>(ys_t, z_t, out_norm_g, out_norm_b, out_proj_w, x_cmaj,
                                   ln2_g, ln2_b, fc1_w, fc1_b, fc2_w, fc2_b, (float*)d_out);
}

// Round 12
// 291.675 us; speedup vs baseline: 1.0036x; 1.0036x over previous
//
#include <hip/hip_runtime.h>
#include <math.h>

// Problem dims
#define BL    6
#define CCH   64
#define C3    192
#define L2    1024
#define DIC   128
#define NST   16
#define K4    4
#define PSTR  1088   // padded plane stride: 34 rows * 32 cols
#define NCH   32     // scan chunks per sequence (32 steps each)

#define LOG2E 1.44269504088896340736f
#define LN2C  0.69314718055994530942f

typedef float f2 __attribute__((ext_vector_type(2)));
__device__ __forceinline__ f2 mkf2(float a, float b){ f2 r; r.x=a; r.y=b; return r; }
__device__ __forceinline__ f2 fma2(f2 a, float b, f2 c){
  f2 bb; bb.x=b; bb.y=b;
  return __builtin_elementwise_fma(a, bb, c);
}

__device__ __forceinline__ float fexp(float x){ return __builtin_amdgcn_exp2f(x*LOG2E); }
__device__ __forceinline__ float fsilu(float x){ return x * __builtin_amdgcn_rcpf(1.f + fexp(-x)); }
__device__ __forceinline__ float fsoftplus(float x){
  if (x > 20.f) return x;
  return __builtin_amdgcn_logf(1.f + fexp(x)) * LN2C;
}
__device__ __forceinline__ float fgelu(float x){
  return 0.5f*x*(1.f + erff(x*0.70710678118654752440f));
}

// ---------------- k1: per-pixel LN + concat; GN1 partials. 768 blocks (8 px each).
__global__ __launch_bounds__(256) void k_ln2d(const float* __restrict__ img,
    const float* __restrict__ dz, const float* __restrict__ sg,
    const float* __restrict__ g, const float* __restrict__ b, float* __restrict__ x3c,
    float* __restrict__ psum1, float* __restrict__ psq1){
  __shared__ float ps[4][8], pq[4][8], gs[4], gq[4];
  int s = blockIdx.x >> 7;
  int pg = blockIdx.x & 127;
  int tid = threadIdx.x;
  int px = tid & 7; int cg = tid >> 3;
  int wv = tid >> 6; int lane = tid & 63;
  int p = pg*8 + px;
  int bsmp = s/3;
  const float* fr = img + (size_t)s*CCH*L2;
  float vals[2]; float sm=0.f, sq=0.f;
  #pragma unroll
  for (int j=0;j<2;++j){
    int c = cg*2 + j;
    float v = fr[c*L2 + p];
    vals[j]=v; sm+=v; sq+=v*v;
  }
  sm += __shfl_xor(sm,8,64);  sq += __shfl_xor(sq,8,64);
  sm += __shfl_xor(sm,16,64); sq += __shfl_xor(sq,16,64);
  sm += __shfl_xor(sm,32,64); sq += __shfl_xor(sq,32,64);
  if (lane < 8){ ps[wv][lane]=sm; pq[wv][lane]=sq; }
  __syncthreads();
  sm = ps[0][px]+ps[1][px]+ps[2][px]+ps[3][px];
  sq = pq[0][px]+pq[1][px]+pq[2][px]+pq[3][px];
  float mean = sm*(1.f/CCH); float var = sq*(1.f/CCH)-mean*mean;
  float rs = rsqrtf(var + 1e-6f);
  float* o = x3c + (size_t)s*C3*L2;
  const float* dzp = dz + (size_t)bsmp*CCH*L2;
  const float* sgp = sg + (size_t)bsmp*CCH*L2;
  float gsm=0.f, gsq=0.f;
  #pragma unroll
  for (int j=0;j<2;++j){
    int c = cg*2+j;
    float dzv = dzp[c*L2+p];
    float nv  = (vals[j]-mean)*rs*g[c] + b[c];
    float sgv = sgp[c*L2+p];
    o[c*L2+p] = dzv;
    o[(CCH+c)*L2+p] = nv;
    o[(2*CCH+c)*L2+p] = sgv;
    gsm += dzv+nv+sgv; gsq += dzv*dzv+nv*nv+sgv*sgv;
  }
  for (int m=1;m<64;m<<=1){ gsm+=__shfl_xor(gsm,m,64); gsq+=__shfl_xor(gsq,m,64); }
  if (lane==0){ gs[wv]=gsm; gq[wv]=gsq; }
  __syncthreads();
  if (tid==0){
    psum1[blockIdx.x] = gs[0]+gs[1]+gs[2]+gs[3];
    psq1 [blockIdx.x] = gq[0]+gq[1]+gq[2]+gq[3];
  }
}

// ---------------- k2: MERGED gnact1 (blocks 0..1151) + skip 1x1 (blocks 1152..1535)
__global__ __launch_bounds__(256) void k_gnact1_skip(const float* __restrict__ x3c,
    const float* __restrict__ psum, const float* __restrict__ psq,
    const float* __restrict__ g, const float* __restrict__ b,
    const float* __restrict__ wsk,
    float* __restrict__ xact1, float* __restrict__ part){
  int bx = blockIdx.x;
  int tid = threadIdx.x;
  if (bx < 1152){
    int s = bx / C3; int c = bx % C3;
    float sm=0.f, sq=0.f;
    for (int i=0;i<128;++i){ sm += psum[s*128+i]; sq += psq[s*128+i]; }
    float mean = sm*(1.f/(C3*L2));
    float var = sq*(1.f/(C3*L2)) - mean*mean;
    float rs = rsqrtf(var + 1e-5f);
    float gc = g[c]*rs; float bc = b[c] - mean*rs*g[c];
    float4 v = *(const float4*)(x3c + (size_t)bx*1024 + tid*4);
    float4 o; o.x = fsilu(v.x*gc+bc); o.y = fsilu(v.y*gc+bc);
    o.z = fsilu(v.z*gc+bc); o.w = fsilu(v.w*gc+bc);
    float* pl = xact1 + (size_t)bx*PSTR;
    *(float4*)(pl + 32 + tid*4) = o;
    float4 z4 = make_float4(0.f,0.f,0.f,0.f);
    if (tid < 8)  *(float4*)(pl + tid*4) = z4;
    else if (tid < 16) *(float4*)(pl + 1056 + (tid-8)*4) = z4;
  } else {
    // skip 1x1 (2 roles x 96 ci), packed over co pair
    int t = bx - 1152;
    int role = t & 1; int cop = (t>>1)&31; int s = t >> 6;
    int co0 = cop*2, co1 = co0+1;
    int row = tid>>3; int q = tid&7; int col0 = q*4;
    int p = row*32+col0;
    f2 a[4];
    #pragma unroll
    for (int i=0;i<4;++i){ a[i].x=0.f; a[i].y=0.f; }
    int ci0 = role*96;
    const float* x3 = x3c + ((size_t)s*C3 + ci0)*L2 + p;
    const float* w0p = wsk + co0*C3 + ci0;
    const float* w1p = wsk + co1*C3 + ci0;
    #pragma unroll 4
    for (int ci=0; ci<96; ++ci){
      float4 v = *(const float4*)(x3 + (size_t)ci*L2);
      f2 w = mkf2(w0p[ci], w1p[ci]);
      a[0] = fma2(w, v.x, a[0]);
      a[1] = fma2(w, v.y, a[1]);
      a[2] = fma2(w, v.z, a[2]);
      a[3] = fma2(w, v.w, a[3]);
    }
    float* pp = part + (size_t)(4+role)*(BL*CCH*L2) + ((size_t)s*CCH+co0)*L2 + p;
    *(float4*)pp = make_float4(a[0].x,a[1].x,a[2].x,a[3].x);
    *(float4*)(pp+L2) = make_float4(a[0].y,a[1].y,a[2].y,a[3].y);
  }
}

// ---------------- gnact2 (generic)
__global__ __launch_bounds__(256) void k_gnact_pad(const float* __restrict__ x,
    const float* __restrict__ psum, const float* __restrict__ psq,
    const float* __restrict__ g, const float* __restrict__ b,
    int ch, int parts, float inv_n, float eps, float* __restrict__ out){
  int bx = blockIdx.x;
  int s = bx / ch; int c = bx % ch;
  int tid = threadIdx.x;
  float sm=0.f, sq=0.f;
  for (int i=0;i<parts;++i){ sm += psum[s*parts+i]; sq += psq[s*parts+i]; }
  float mean = sm*inv_n;
  float var = sq*inv_n - mean*mean;
  float rs = rsqrtf(var + eps);
  float gc = g[c]*rs; float bc = b[c] - mean*rs*g[c];
  float4 v = *(const float4*)(x + (size_t)bx*1024 + tid*4);
  float4 o; o.x = fsilu(v.x*gc+bc); o.y = fsilu(v.y*gc+bc);
  o.z = fsilu(v.z*gc+bc); o.w = fsilu(v.w*gc+bc);
  float* pl = out + (size_t)bx*PSTR;
  *(float4*)(pl + 32 + tid*4) = o;
  float4 z4 = make_float4(0.f,0.f,0.f,0.f);
  if (tid < 8)  *(float4*)(pl + tid*4) = z4;
  else if (tid < 16) *(float4*)(pl + 1056 + (tid-8)*4) = z4;
}

// packed conv helpers: a[4] = (co0,co1) accumulators per px
__device__ __forceinline__ void conv_row_acc2(f2* a, float4 mid, float lf, float rt,
    const float* wp0, const float* wp1){
  f2 w0 = mkf2(wp0[0],wp1[0]);
  f2 w1 = mkf2(wp0[1],wp1[1]);
  f2 w2 = mkf2(wp0[2],wp1[2]);
  a[0] = fma2(w0,lf,   fma2(w1,mid.x, fma2(w2,mid.y, a[0])));
  a[1] = fma2(w0,mid.x,fma2(w1,mid.y, fma2(w2,mid.z, a[1])));
  a[2] = fma2(w0,mid.y,fma2(w1,mid.z, fma2(w2,mid.w, a[2])));
  a[3] = fma2(w0,mid.z,fma2(w1,mid.w, fma2(w2,rt,    a[3])));
}

__device__ __forceinline__ void conv_ci_body2(float4 m0, float4 m1, float4 m2, int q,
    const float* wp0, const float* wp1, f2* a){
  float lf0=__shfl_up(m0.w,1,64), rt0=__shfl_down(m0.x,1,64);
  float lf1=__shfl_up(m1.w,1,64), rt1=__shfl_down(m1.x,1,64);
  float lf2=__shfl_up(m2.w,1,64), rt2=__shfl_down(m2.x,1,64);
  if (q==0){ lf0=0.f; lf1=0.f; lf2=0.f; }
  if (q==7){ rt0=0.f; rt1=0.f; rt2=0.f; }
  conv_row_acc2(a,m0,lf0,rt0, wp0+0, wp1+0);
  conv_row_acc2(a,m1,lf1,rt1, wp0+3, wp1+3);
  conv_row_acc2(a,m2,lf2,rt2, wp0+6, wp1+6);
}

// ---------------- k3: conv1 192ci->64co, split-K=12 (16 ci each), 2304 blocks
__global__ __launch_bounds__(256) void k_conv1_split(const float* __restrict__ xact,
    const float* __restrict__ w, float* __restrict__ part){
  int bx = blockIdx.x; int kk = bx % 12; int r = bx / 12;
  int cop = r & 31; int s = r >> 5;
  int co0 = cop*2, co1 = co0+1;
  int tid = threadIdx.x; int row = tid>>3; int q = tid&7; int col0 = q*4;
  f2 a[4];
  #pragma unroll
  for (int i=0;i<4;++i){ a[i].x=0.f; a[i].y=0.f; }
  int ci0 = kk*16;
  const float* pl = xact + ((size_t)s*C3 + ci0)*PSTR + row*32 + col0;
  const float* wp0 = w + (size_t)(co0*C3 + ci0)*9;
  const float* wp1 = w + (size_t)(co1*C3 + ci0)*9;
  float4 m0 = *(const float4*)(pl);
  float4 m1 = *(const float4*)(pl+32);
  float4 m2 = *(const float4*)(pl+64);
  #pragma unroll 2
  for (int i=0;i<16;++i){
    const float* pn = pl + (i<15 ? PSTR : 0);
    float4 n0 = *(const float4*)(pn);
    float4 n1 = *(const float4*)(pn+32);
    float4 n2 = *(const float4*)(pn+64);
    conv_ci_body2(m0,m1,m2,q, wp0, wp1, a);
    wp0 += 9; wp1 += 9; pl = pn; m0=n0; m1=n1; m2=n2;
  }
  float* pp = part + (size_t)kk*(BL*CCH*L2) + ((size_t)s*CCH+co0)*L2 + row*32+col0;
  *(float4*)pp = make_float4(a[0].x,a[1].x,a[2].x,a[3].x);
  *(float4*)(pp+L2) = make_float4(a[0].y,a[1].y,a[2].y,a[3].y);
}

// ---------------- k4: reduce conv1 partials (12) + bias -> h1; GN2 partials
__global__ __launch_bounds__(256) void k_reduce1(const float* __restrict__ part,
    const float* __restrict__ bias, float* __restrict__ h1,
    float* __restrict__ psum2, float* __restrict__ psq2){
  int co = blockIdx.x & 63; int s = blockIdx.x >> 6;
  size_t ofs = ((size_t)s*CCH+co)*L2 + threadIdx.x*4;
  const size_t stride = (size_t)BL*CCH*L2;
  float4 acc = *(const float4*)(part + ofs);
  #pragma unroll
  for (int kk=1;kk<12;++kk){
    float4 r = *(const float4*)(part + (size_t)kk*stride + ofs);
    acc.x += r.x; acc.y += r.y; acc.z += r.z; acc.w += r.w;
  }
  float bv = bias[co];
  acc.x += bv; acc.y += bv; acc.z += bv; acc.w += bv;
  *(float4*)(h1 + ofs) = acc;
  float sm = acc.x+acc.y+acc.z+acc.w;
  float sq = acc.x*acc.x+acc.y*acc.y+acc.z*acc.z+acc.w*acc.w;
  for (int m=1;m<64;m<<=1){ sm+=__shfl_xor(sm,m,64); sq+=__shfl_xor(sq,m,64); }
  __shared__ float s_sm[4], s_sq[4];
  int wv = threadIdx.x>>6;
  if ((threadIdx.x&63)==0){ s_sm[wv]=sm; s_sq[wv]=sq; }
  __syncthreads();
  if (threadIdx.x==0){
    psum2[blockIdx.x] = s_sm[0]+s_sm[1]+s_sm[2]+s_sm[3];
    psq2 [blockIdx.x] = s_sq[0]+s_sq[1]+s_sq[2]+s_sq[3];
  }
}

// ---------------- k6: conv2 FOUR roles x 16ci, 768 blocks
__global__ __launch_bounds__(256) void k_conv2_split(const float* __restrict__ xact2,
    const float* __restrict__ w2, float* __restrict__ part){
  int bx = blockIdx.x; int role = bx & 3; int t = bx >> 2;
  int cop = t & 31; int s = t >> 5;
  int co0 = cop*2, co1 = co0+1;
  int tid = threadIdx.x; int row = tid>>3; int q = tid&7; int col0 = q*4;
  int p = row*32+col0;
  f2 a[4];
  #pragma unroll
  for (int i=0;i<4;++i){ a[i].x=0.f; a[i].y=0.f; }
  int ci0 = role*16;
  const float* pl = xact2 + ((size_t)s*CCH + ci0)*PSTR + row*32 + col0;
  const float* wp0 = w2 + (size_t)(co0*CCH + ci0)*9;
  const float* wp1 = w2 + (size_t)(co1*CCH + ci0)*9;
  float4 m0 = *(const float4*)(pl);
  float4 m1 = *(const float4*)(pl+32);
  float4 m2 = *(const float4*)(pl+64);
  #pragma unroll 2
  for (int i=0;i<16;++i){
    const float* pn = pl + (i<15 ? PSTR : 0);
    float4 n0 = *(const float4*)(pn);
    float4 n1 = *(const float4*)(pn+32);
    float4 n2 = *(const float4*)(pn+64);
    conv_ci_body2(m0,m1,m2,q, wp0, wp1, a);
    wp0 += 9; wp1 += 9; pl = pn; m0=n0; m1=n1; m2=n2;
  }
  float* pp = part + (size_t)role*(BL*CCH*L2) + ((size_t)s*CCH+co0)*L2 + p;
  *(float4*)pp = make_float4(a[0].x,a[1].x,a[2].x,a[3].x);
  *(float4*)(pp+L2) = make_float4(a[0].y,a[1].y,a[2].y,a[3].y);
}

// ---------------- k7: reduce2(6 slots) + ln1 + in_proj fused, oq split x8, packed GEMM
__global__ __launch_bounds__(256) void k_red2_ln1_inproj(const float* __restrict__ part,
    const float* __restrict__ b2, const float* __restrict__ bsk,
    const float* __restrict__ g, const float* __restrict__ b,
    const float* __restrict__ W,
    float* __restrict__ x_cmaj, float* __restrict__ xc, float* __restrict__ z_t){
  __shared__ float xn_s[64*65];
  int bx = blockIdx.x; int oq = bx & 7; int pg = (bx>>3)&15; int s = bx>>7;
  int p0 = pg*64;
  int tid = threadIdx.x;
  const size_t stride = (size_t)BL*CCH*L2;
  #pragma unroll
  for (int kq=0;kq<4;++kq){
    int f = kq*256 + tid;
    int co = f >> 4; int px4 = (f & 15)*4;
    size_t ofs = ((size_t)s*CCH+co)*L2 + p0 + px4;
    float4 r0 = *(const float4*)(part + ofs);
    float4 r1 = *(const float4*)(part + stride + ofs);
    float4 r2 = *(const float4*)(part + 2*stride + ofs);
    float4 r3 = *(const float4*)(part + 3*stride + ofs);
    float4 r4 = *(const float4*)(part + 4*stride + ofs);
    float4 r5 = *(const float4*)(part + 5*stride + ofs);
    float bv = b2[co]+bsk[co];
    float4 o;
    o.x = ((r0.x+r1.x)+(r2.x+r3.x))+(r4.x+r5.x)+bv;
    o.y = ((r0.y+r1.y)+(r2.y+r3.y))+(r4.y+r5.y)+bv;
    o.z = ((r0.z+r1.z)+(r2.z+r3.z))+(r4.z+r5.z)+bv;
    o.w = ((r0.w+r1.w)+(r2.w+r3.w))+(r4.w+r5.w)+bv;
    if (oq == 0) *(float4*)(x_cmaj + ofs) = o;
    xn_s[(px4+0)*65 + co] = o.x;
    xn_s[(px4+1)*65 + co] = o.y;
    xn_s[(px4+2)*65 + co] = o.z;
    xn_s[(px4+3)*65 + co] = o.w;
  }
  __syncthreads();
  {
    int wv = __builtin_amdgcn_readfirstlane(tid>>6); int lane = tid&63;
    for (int j=0;j<16;++j){
      int pl = wv*16 + j;
      float v = xn_s[pl*65 + lane];
      float sm = v, sq = v*v;
      for (int m=1;m<64;m<<=1){ sm += __shfl_xor(sm,m,64); sq += __shfl_xor(sq,m,64); }
      float mean = sm*(1.f/64.f); float var = sq*(1.f/64.f) - mean*mean;
      float rs = rsqrtf(var + 1e-5f);
      xn_s[pl*65 + lane] = (v-mean)*rs*g[lane] + b[lane];
    }
  }
  __syncthreads();
  int px_l = tid & 63;
  int og = __builtin_amdgcn_readfirstlane(tid >> 6);
  int o0 = oq*32 + og*8;
  f2 acc[4];
  #pragma unroll
  for (int oi=0;oi<4;++oi){ acc[oi].x=0.f; acc[oi].y=0.f; }
  for (int c=0;c<64;++c){
    float xv = xn_s[px_l*65 + c];
    #pragma unroll
    for (int oi=0;oi<4;++oi)
      acc[oi] = fma2(mkf2(W[(o0+2*oi)*64 + c], W[(o0+2*oi+1)*64 + c]), xv, acc[oi]);
  }
  int p = p0 + px_l;
  if (oq < 4){
    #pragma unroll
    for (int oi=0;oi<4;++oi){
      xc[((size_t)s*DIC + o0 + 2*oi)*L2 + p]   = acc[oi].x;
      xc[((size_t)s*DIC + o0 + 2*oi+1)*L2 + p] = acc[oi].y;
    }
  } else {
    #pragma unroll
    for (int oi=0;oi<4;++oi){
      z_t[((size_t)s*DIC + (o0-128) + 2*oi)*L2 + p]   = acc[oi].x;
      z_t[((size_t)s*DIC + (o0-128) + 2*oi+1)*L2 + p] = acc[oi].y;
    }
  }
}

// ---------------- k8: x_proj + INLINE depthwise 3x3 + SiLU — HALF-SPLIT, 768 blocks
// half0: dt ranks (rows 0-3) + B (rows 4-19), 5 outputs/thread
// half1: C (rows 20-35), 4 outputs/thread, + u_t write (k==0)
__global__ __launch_bounds__(256) void k_xproj_dt(const float* __restrict__ xc,
    const float* __restrict__ dww, const float* __restrict__ dwb,
    const float* __restrict__ W,
    float* __restrict__ dtr, float* __restrict__ Bp, float* __restrict__ Cp,
    float* __restrict__ u_t){
  __shared__ float smem[128*68];
  int bx = blockIdx.x; int half = bx & 1; int pg = (bx>>1) & 15; int sk = bx >> 5;
  int k = sk & 3; int s = sk >> 2;
  int tid = threadIdx.x;
  // dwconv+silu into smem (both halves duplicate this cheap fill)
  for (int i = tid; i < 128*16; i += 256){
    int dr = i>>4; int j4 = (i&15)*4;
    int rw = j4>>5; int col0 = j4 & 31;
    int gr = pg*2 + rw;
    int q = i&7;
    const float* xr = xc + ((size_t)s*DIC+dr)*L2;
    const float* wp = dww + dr*9;
    float bv = dwb[dr];
    float4 acc = make_float4(bv,bv,bv,bv);
    #pragma unroll
    for (int dy=-1;dy<=1;++dy){
      int r = gr+dy;
      float4 mid = make_float4(0.f,0.f,0.f,0.f);
      if (0<=r && r<32) mid = *(const float4*)(xr + r*32 + col0);
      float lf = __shfl_up(mid.w,1,64); if(q==0) lf=0.f;
      float rt = __shfl_down(mid.x,1,64); if(q==7) rt=0.f;
      float w0=wp[(dy+1)*3], w1=wp[(dy+1)*3+1], w2=wp[(dy+1)*3+2];
      acc.x = fmaf(w0,lf,   fmaf(w1,mid.x, fmaf(w2,mid.y, acc.x)));
      acc.y = fmaf(w0,mid.x,fmaf(w1,mid.y, fmaf(w2,mid.z, acc.y)));
      acc.z = fmaf(w0,mid.y,fmaf(w1,mid.z, fmaf(w2,mid.w, acc.z)));
      acc.w = fmaf(w0,mid.z,fmaf(w1,mid.w, fmaf(w2,rt,    acc.w)));
    }
    acc.x = fsilu(acc.x); acc.y = fsilu(acc.y); acc.z = fsilu(acc.z); acc.w = fsilu(acc.w);
    *(float4*)&smem[dr*68 + j4] = acc;
  }
  __syncthreads();
  int px = tid & 63;
  int cgrp = __builtin_amdgcn_readfirstlane(tid >> 6);
  if (half == 1){
    if (k == 0){
      float* ub = u_t + ((size_t)(s*L2) + pg*64)*DIC;
      for (int i = tid; i < 64*128; i += 256){
        int px2 = i>>7; int dd = i&127;
        ub[(size_t)px2*DIC + dd] = smem[dd*68 + px2];
      }
    }
    // C rows: c0 = 20 + cgrp*4
    int c0 = 20 + cgrp*4;
    const float* wb = W + (size_t)(k*36 + c0)*DIC;
    f2 acc2[2];
    acc2[0].x=0.f; acc2[0].y=0.f; acc2[1].x=0.f; acc2[1].y=0.f;
    for (int d=0; d<DIC; ++d){
      float xv = smem[d*68 + px];
      acc2[0] = fma2(mkf2(wb[0*DIC+d], wb[1*DIC+d]), xv, acc2[0]);
      acc2[1] = fma2(mkf2(wb[2*DIC+d], wb[3*DIC+d]), xv, acc2[1]);
    }
    __syncthreads();
    smem[(c0+0)*68 + px] = acc2[0].x;
    smem[(c0+1)*68 + px] = acc2[0].y;
    smem[(c0+2)*68 + px] = acc2[1].x;
    smem[(c0+3)*68 + px] = acc2[1].y;
    __syncthreads();
    float* Cb = Cp + ((size_t)sk*L2 + pg*64)*NST;
    for (int i = tid; i < 1024; i += 256){
      int pp = i>>4; int n = i&15;
      Cb[pp*NST + n] = smem[(20+n)*68 + pp];
    }
  } else {
    // dt + B rows: c0 = cgrp*5, 5 outputs
    int c0 = cgrp*5;
    const float* wb = W + (size_t)(k*36 + c0)*DIC;
    f2 acc2[2]; float acc4 = 0.f;
    acc2[0].x=0.f; acc2[0].y=0.f; acc2[1].x=0.f; acc2[1].y=0.f;
    for (int d=0; d<DIC; ++d){
      float xv = smem[d*68 + px];
      acc2[0] = fma2(mkf2(wb[0*DIC+d], wb[1*DIC+d]), xv, acc2[0]);
      acc2[1] = fma2(mkf2(wb[2*DIC+d], wb[3*DIC+d]), xv, acc2[1]);
      acc4 = fmaf(wb[4*DIC+d], xv, acc4);
    }
    __syncthreads();
    smem[(c0+0)*68 + px] = acc2[0].x;
    smem[(c0+1)*68 + px] = acc2[0].y;
    smem[(c0+2)*68 + px] = acc2[1].x;
    smem[(c0+3)*68 + px] = acc2[1].y;
    smem[(c0+4)*68 + px] = acc4;
    __syncthreads();
    {
      int pp = tid >> 2; int r = tid & 3;
      dtr[((size_t)sk*L2 + pg*64 + pp)*4 + r] = smem[r*68 + pp];
    }
    float* Bb = Bp + ((size_t)sk*L2 + pg*64)*NST;
    for (int i = tid; i < 1024; i += 256){
      int pp = i>>4; int n = i&15;
      Bb[pp*NST + n] = smem[(4+n)*68 + pp];
    }
  }
}

// scan pixel for direction k, chunk ch (32 steps), step j
__device__ __forceinline__ int scan_pix32(int ch, int j, int k){
  if (k==0) return ch*32 + j;
  if (k==1) return j*32 + ch;
  if (k==2) return 1023 - (ch*32 + j);
  return 1023 - (j*32 + ch);
}

// half-state step (8 of 16 SSM states per thread)
struct StepH { float4 dt4; float uv; float4 B0,B1; };
__device__ __forceinline__ StepH loadH(const float* dr, const float* ub, const float* Bb, int p){
  StepH r;
  r.dt4 = *(const float4*)(dr + (size_t)p*4);
  r.uv = ub[(size_t)p*DIC];
  const float* bp = Bb + p*NST;   // Bb pre-offset by nh*8
  r.B0 = *(const float4*)bp; r.B1 = *(const float4*)(bp+4);
  return r;
}
__device__ __forceinline__ float dt_eval(float4 w4, float bb, float4 d4){
  return fsoftplus(fmaf(w4.x,d4.x,fmaf(w4.y,d4.y,fmaf(w4.z,d4.z,fmaf(w4.w,d4.w,bb)))));
}

// check: aco[n] == (gbase+n+1)*acoR for all local n (A = -(n+1) structure)
__device__ __forceinline__ bool aco_linear(const float* aco, float acoR, int gbase){
  bool ok = true;
  #pragma unroll
  for (int n=0;n<8;++n){
    float ideal = (float)(gbase+n+1) * acoR;
    ok = ok && (fabsf(aco[n]-ideal) <= 1e-5f*fabsf(ideal) + 1e-12f);
  }
  return ok;
}

// ---------------- k9: scan pass 1, n-split, 768 blocks
__global__ __launch_bounds__(256,4) void k_scan_part3(const float* __restrict__ dtr,
    const float* __restrict__ dtw, const float* __restrict__ dtb,
    const float* __restrict__ u_t, const float* __restrict__ Bp,
    const float* __restrict__ A_logs, float* __restrict__ hend, float* __restrict__ Ssum){
  int bx = blockIdx.x; int ch = bx & 31; int sk = bx >> 5;
  int k = sk & 3; int s = sk >> 2;
  int tid = threadIdx.x; int d = tid >> 1; int nh = tid & 1;
  float aco[8];
  float acoR = -LOG2E * fexp(A_logs[(size_t)(k*DIC+d)*NST]);
  {
    const float* ab = A_logs + (size_t)(k*DIC+d)*NST + nh*8;
    #pragma unroll
    for (int n=0;n<8;++n) aco[n] = -LOG2E * fexp(ab[n]);
  }
  bool fast = aco_linear(aco, acoR, nh*8);
  float aco0 = aco[0];
  float4 w4 = *(const float4*)(dtw + (size_t)(k*DIC+d)*4);
  float bb = dtb[k*DIC+d];
  float h[8]; float Sacc = 0.f;
  #pragma unroll
  for (int n=0;n<8;++n) h[n]=0.f;
  const float* dr = dtr + (size_t)sk*L2*4;
  const float* ub = u_t + (size_t)s*L2*DIC + d;
  const float* Bb = Bp + (size_t)sk*L2*NST + nh*8;
  StepH cur = loadH(dr, ub, Bb, scan_pix32(ch, 0, k));
  if (fast){
    #pragma unroll 4
    for (int j=0;j<32;++j){
      StepH nxt;
      if (j < 31) nxt = loadH(dr, ub, Bb, scan_pix32(ch, j+1, k));
      float dtv = dt_eval(w4, bb, cur.dt4);
      Sacc += dtv;
      float tv = dtv*cur.uv;
      float rr = __builtin_amdgcn_exp2f(dtv*acoR);
      float a_ = __builtin_amdgcn_exp2f(dtv*aco0);
      h[0] = fmaf(a_, h[0], tv*cur.B0.x);
      a_ *= rr; h[1] = fmaf(a_, h[1], tv*cur.B0.y);
      a_ *= rr; h[2] = fmaf(a_, h[2], tv*cur.B0.z);
      a_ *= rr; h[3] = fmaf(a_, h[3], tv*cur.B0.w);
      a_ *= rr; h[4] = fmaf(a_, h[4], tv*cur.B1.x);
      a_ *= rr; h[5] = fmaf(a_, h[5], tv*cur.B1.y);
      a_ *= rr; h[6] = fmaf(a_, h[6], tv*cur.B1.z);
      a_ *= rr; h[7] = fmaf(a_, h[7], tv*cur.B1.w);
      cur = nxt;
    }
  } else {
    #pragma unroll 4
    for (int j=0;j<32;++j){
      StepH nxt;
      if (j < 31) nxt = loadH(dr, ub, Bb, scan_pix32(ch, j+1, k));
      float dtv = dt_eval(w4, bb, cur.dt4);
      Sacc += dtv;
      float tv = dtv*cur.uv;
      #define PSTEP(NI, BV) { float a_ = __builtin_amdgcn_exp2f(dtv*aco[NI]); \
        h[NI] = fmaf(a_, h[NI], tv*(BV)); }
      PSTEP(0,cur.B0.x) PSTEP(1,cur.B0.y) PSTEP(2,cur.B0.z) PSTEP(3,cur.B0.w)
      PSTEP(4,cur.B1.x) PSTEP(5,cur.B1.y) PSTEP(6,cur.B1.z) PSTEP(7,cur.B1.w)
      #undef PSTEP
      cur = nxt;
    }
  }
  size_t base = ((size_t)(sk*NCH + ch)*DIC + d)*NST + nh*8;
  *(float4*)(hend + base)     = make_float4(h[0],h[1],h[2],h[3]);
  *(float4*)(hend + base + 4) = make_float4(h[4],h[5],h[6],h[7]);
  if (nh == 0) Ssum[(size_t)(sk*NCH + ch)*DIC + d] = Sacc;
}

// ---------------- k10: full scan + y output, n-split, 768 blocks
// (scan_fix eliminated: each block computes its own chunk-prefix from hend/Ssum)
__global__ __launch_bounds__(256,4) void k_scan_y3(const float* __restrict__ dtr,
    const float* __restrict__ dtw, const float* __restrict__ dtb,
    const float* __restrict__ u_t, const float* __restrict__ Bp, const float* __restrict__ Cp,
    const float* __restrict__ A_logs, const float* __restrict__ Ds,
    const float* __restrict__ hend, const float* __restrict__ Ssum,
    float* __restrict__ ys_t){
  int bx = blockIdx.x; int ch = bx & 31; int sk = bx >> 5;
  int k = sk & 3; int s = sk >> 2;
  int tid = threadIdx.x; int d = tid >> 1; int nh = tid & 1;
  float aco[8];
  float acoR = -LOG2E * fexp(A_logs[(size_t)(k*DIC+d)*NST]);
  {
    const float* ab = A_logs + (size_t)(k*DIC+d)*NST + nh*8;
    #pragma unroll
    for (int n=0;n<8;++n) aco[n] = -LOG2E * fexp(ab[n]);
  }
  bool fast = aco_linear(aco, acoR, nh*8);
  float aco0 = aco[0];
  float4 w4 = *(const float4*)(dtw + (size_t)(k*DIC+d)*4);
  float bb = dtb[k*DIC+d];
  float Dv = Ds[k*DIC+d];
  // inline chunk-prefix: H over chunks 0..ch-1 (same recurrence as old scan_fix)
  float h[8];
  #pragma unroll
  for (int n=0;n<8;++n) h[n]=0.f;
  {
    const float* Sb = Ssum + (size_t)sk*NCH*DIC + d;
    const float* Hb = hend + ((size_t)sk*NCH*DIC + d)*NST + nh*8;
    for (int cc=0; cc<ch; ++cc){
      float Sv = Sb[(size_t)cc*DIC];
      float4 e0 = *(const float4*)(Hb + (size_t)cc*DIC*NST);
      float4 e1 = *(const float4*)(Hb + (size_t)cc*DIC*NST + 4);
      if (fast){
        float rr = __builtin_amdgcn_exp2f(acoR*Sv);
        float a_ = __builtin_amdgcn_exp2f(aco0*Sv);
        h[0] = fmaf(a_, h[0], e0.x);
        a_ *= rr; h[1] = fmaf(a_, h[1], e0.y);
        a_ *= rr; h[2] = fmaf(a_, h[2], e0.z);
        a_ *= rr; h[3] = fmaf(a_, h[3], e0.w);
        a_ *= rr; h[4] = fmaf(a_, h[4], e1.x);
        a_ *= rr; h[5] = fmaf(a_, h[5], e1.y);
        a_ *= rr; h[6] = fmaf(a_, h[6], e1.z);
        a_ *= rr; h[7] = fmaf(a_, h[7], e1.w);
      } else {
        float he[8] = {e0.x,e0.y,e0.z,e0.w,e1.x,e1.y,e1.z,e1.w};
        #pragma unroll
        for (int n=0;n<8;++n){
          float pa = __builtin_amdgcn_exp2f(aco[n]*Sv);
          h[n] = fmaf(pa, h[n], he[n]);
        }
      }
    }
  }
  const float* dr = dtr + (size_t)sk*L2*4;
  const float* ub = u_t + (size_t)s*L2*DIC + d;
  const float* Bb = Bp + (size_t)sk*L2*NST + nh*8;
  const float* Cb = Cp + (size_t)sk*L2*NST + nh*8;
  float* yb = ys_t + (size_t)sk*L2*DIC + d;
  int pcur = scan_pix32(ch, 0, k);
  StepH cur = loadH(dr, ub, Bb, pcur);
  float4 Cc0 = *(const float4*)(Cb + pcur*NST);
  float4 Cc1 = *(const float4*)(Cb + pcur*NST + 4);
  if (fast){
    #pragma unroll 4
    for (int j=0;j<32;++j){
      StepH nxt; float4 Cn0, Cn1; int pn = pcur;
      if (j < 31){
        pn = scan_pix32(ch, j+1, k);
        nxt = loadH(dr, ub, Bb, pn);
        Cn0 = *(const float4*)(Cb + pn*NST);
        Cn1 = *(const float4*)(Cb + pn*NST + 4);
      }
      float dtv = dt_eval(w4, bb, cur.dt4);
      float tv = dtv*cur.uv;
      float y0=0.f, y1=0.f, y2=0.f, y3=0.f;
      float rr = __builtin_amdgcn_exp2f(dtv*acoR);
      float a_ = __builtin_amdgcn_exp2f(dtv*aco0);
      h[0] = fmaf(a_, h[0], tv*cur.B0.x); y0 = fmaf(h[0], Cc0.x, y0);
      a_ *= rr; h[1] = fmaf(a_, h[1], tv*cur.B0.y); y1 = fmaf(h[1], Cc0.y, y1);
      a_ *= rr; h[2] = fmaf(a_, h[2], tv*cur.B0.z); y2 = fmaf(h[2], Cc0.z, y2);
      a_ *= rr; h[3] = fmaf(a_, h[3], tv*cur.B0.w); y3 = fmaf(h[3], Cc0.w, y3);
      a_ *= rr; h[4] = fmaf(a_, h[4], tv*cur.B1.x); y0 = fmaf(h[4], Cc1.x, y0);
      a_ *= rr; h[5] = fmaf(a_, h[5], tv*cur.B1.y); y1 = fmaf(h[5], Cc1.y, y1);
      a_ *= rr; h[6] = fmaf(a_, h[6], tv*cur.B1.z); y2 = fmaf(h[6], Cc1.z, y2);
      a_ *= rr; h[7] = fmaf(a_, h[7], tv*cur.B1.w); y3 = fmaf(h[7], Cc1.w, y3);
      float py = (y0+y1)+(y2+y3);
      float tot = py + __shfl_xor(py, 1, 64);
      if (nh == 0) yb[(size_t)pcur*DIC] = fmaf(cur.uv, Dv, tot);
      cur = nxt; Cc0 = Cn0; Cc1 = Cn1; pcur = pn;
    }
  } else {
    #pragma unroll 4
    for (int j=0;j<32;++j){
      StepH nxt; float4 Cn0, Cn1; int pn = pcur;
      if (j < 31){
        pn = scan_pix32(ch, j+1, k);
        nxt = loadH(dr, ub, Bb, pn);
        Cn0 = *(const float4*)(Cb + pn*NST);
        Cn1 = *(const float4*)(Cb + pn*NST + 4);
      }
      float dtv = dt_eval(w4, bb, cur.dt4);
      float tv = dtv*cur.uv;
      float y0=0.f, y1=0.f, y2=0.f, y3=0.f;
      #define YSTEP(NI, BV, CV, YA) { float a_ = __builtin_amdgcn_exp2f(dtv*aco[NI]); \
        h[NI] = fmaf(a_, h[NI], tv*(BV)); YA = fmaf(h[NI], (CV), YA); }
      YSTEP(0,cur.B0.x,Cc0.x,y0) YSTEP(1,cur.B0.y,Cc0.y,y1) YSTEP(2,cur.B0.z,Cc0.z,y2) YSTEP(3,cur.B0.w,Cc0.w,y3)
      YSTEP(4,cur.B1.x,Cc1.x,y0) YSTEP(5,cur.B1.y,Cc1.y,y1) YSTEP(6,cur.B1.z,Cc1.z,y2) YSTEP(7,cur.B1.w,Cc1.w,y3)
      #undef YSTEP
      float py = (y0+y1)+(y2+y3);
      float tot = py + __shfl_xor(py, 1, 64);
      if (nh == 0) yb[(size_t)pcur*DIC] = fmaf(cur.uv, Dv, tot);
      cur = nxt; Cc0 = Cn0; Cc1 = Cn1; pcur = pn;
    }
  }
}

// ---------------- k11: fused tail, 8 px per block, 768 blocks, packed GEMMs
__global__ __launch_bounds__(256) void k_tail(const float* __restrict__ ys_t,
    const float* __restrict__ z_t, const float* __restrict__ ong, const float* __restrict__ onb,
    const float* __restrict__ Wop, const float* __restrict__ x_cmaj,
    const float* __restrict__ g2, const float* __restrict__ b2n,
    const float* __restrict__ w1, const float* __restrict__ b1,
    const float* __restrict__ w2, const float* __restrict__ b2,
    float* __restrict__ out){
  __shared__ float yt[128*9];
  __shared__ float xvt[64*9];
  __shared__ float ts[64*9];
  int s = blockIdx.x >> 7; int pg = blockIdx.x & 127;
  int tid = threadIdx.x;
  {
    int wv = __builtin_amdgcn_readfirstlane(tid>>6); int lane = tid&63;
    int d0 = lane, d1 = lane+64;
    for (int i=0;i<2;++i){
      int px = i*4 + wv; int p = pg*8 + px;
      const float* yb = ys_t + ((size_t)(s*4)*L2 + p)*DIC;
      float ya = yb[d0] + yb[(size_t)L2*DIC + d0] + yb[(size_t)2*L2*DIC + d0] + yb[(size_t)3*L2*DIC + d0];
      float yc = yb[d1] + yb[(size_t)L2*DIC + d1] + yb[(size_t)2*L2*DIC + d1] + yb[(size_t)3*L2*DIC + d1];
      float sm = ya+yc, sq = ya*ya+yc*yc;
      for (int m=1;m<64;m<<=1){ sm+=__shfl_xor(sm,m,64); sq+=__shfl_xor(sq,m,64); }
      float mean = sm*(1.f/128.f); float var = sq*(1.f/128.f)-mean*mean;
      float rs = rsqrtf(var + 1e-5f);
      float yn0 = (ya-mean)*rs*ong[d0] + onb[d0];
      float yn1 = (yc-mean)*rs*ong[d1] + onb[d1];
      float zv0 = z_t[((size_t)s*DIC+d0)*L2 + p];
      float zv1 = z_t[((size_t)s*DIC+d1)*L2 + p];
      yt[d0*9 + px] = yn0 * fsilu(zv0);
      yt[d1*9 + px] = yn1 * fsilu(zv1);
    }
  }
  __syncthreads();
  {
    int px = tid & 7; int cgp = tid >> 3;
    int c0 = cgp*2;
    f2 A; A.x=0.f; A.y=0.f;
    for (int d=0; d<DIC; ++d){
      float yv = yt[d*9 + px];
      A = fma2(mkf2(Wop[(c0+0)*DIC + d], Wop[(c0+1)*DIC + d]), yv, A);
    }
    int p = pg*8 + px;
    size_t base = ((size_t)s*CCH + c0)*L2 + p;
    xvt[(c0+0)*9 + px] = x_cmaj[base]    + A.x;
    xvt[(c0+1)*9 + px] = x_cmaj[base+L2] + A.y;
  }
  __syncthreads();
  int px = tid & 7; int cgp = tid >> 3;
  float sm=0.f, sq=0.f;
  for (int c=0;c<64;++c){ float v = xvt[c*9+px]; sm+=v; sq+=v*v; }
  float mean = sm*(1.f/64.f);
  float rs = rsqrtf(sq*(1.f/64.f) - mean*mean + 1e-5f);
  int o0 = cgp*2;
  f2 T = mkf2(b1[o0], b1[o0+1]);
  for (int c=0;c<64;++c){
    float xn = (xvt[c*9+px]-mean)*rs*g2[c] + b2n[c];
    T = fma2(mkf2(w1[(o0+0)*64 + c], w1[(o0+1)*64 + c]), xn, T);
  }
  ts[(o0+0)*9 + px] = fgelu(T.x);
  ts[(o0+1)*9 + px] = fgelu(T.y);
  __syncthreads();
  int c0 = cgp*2;
  f2 ACC = mkf2(xvt[(c0+0)*9+px] + b2[c0+0], xvt[(c0+1)*9+px] + b2[c0+1]);
  for (int o=0;o<64;++o){
    float tv = ts[o*9+px];
    ACC = fma2(mkf2(w2[(c0+0)*64 + o], w2[(c0+1)*64 + o]), tv, ACC);
  }
  int p = pg*8 + px;
  out[((size_t)s*CCH + c0+0)*L2 + p] = ACC.x;
  out[((size_t)s*CCH + c0+1)*L2 + p] = ACC.y;
}

extern "C" void kernel_launch(void* const* d_in, const int* in_sizes, int n_in,
                              void* d_out, int out_size, void* d_ws, size_t ws_size,
                              hipStream_t stream){
  (void)in_sizes; (void)n_in; (void)out_size; (void)ws_size;
  const float* img      = (const float*)d_in[0];
  const float* dz       = (const float*)d_in[1];
  const float* sg       = (const float*)d_in[2];
  const float* norm_g   = (const float*)d_in[3];
  const float* norm_b   = (const float*)d_in[4];
  const float* gn1_g    = (const float*)d_in[5];
  const float* gn1_b    = (const float*)d_in[6];
  const float* conv1_w  = (const float*)d_in[7];
  const float* conv1_b  = (const float*)d_in[8];
  const float* gn2_g    = (const float*)d_in[9];
  const float* gn2_b    = (const float*)d_in[10];
  const float* conv2_w  = (const float*)d_in[11];
  const float* conv2_b  = (const float*)d_in[12];
  const float* skip_w   = (const float*)d_in[13];
  const float* skip_b   = (const float*)d_in[14];
  const float* ln1_g    = (const float*)d_in[15];
  const float* ln1_b    = (const float*)d_in[16];
  const float* ln2_g    = (const float*)d_in[17];
  const float* ln2_b    = (const float*)d_in[18];
  const float* in_proj_w= (const float*)d_in[19];
  const float* dwconv_w = (const float*)d_in[20];
  const float* dwconv_b = (const float*)d_in[21];
  const float* x_proj_w = (const float*)d_in[22];
  const float* dt_proj_w= (const float*)d_in[23];
  const float* dt_proj_b= (const float*)d_in[24];
  const float* A_logs   = (const float*)d_in[25];
  const float* Ds       = (const float*)d_in[26];
  const float* out_norm_g = (const float*)d_in[27];
  const float* out_norm_b = (const float*)d_in[28];
  const float* out_proj_w = (const float*)d_in[29];
  const float* fc1_w    = (const float*)d_in[30];
  const float* fc1_b    = (const float*)d_in[31];
  const float* fc2_w    = (const float*)d_in[32];
  const float* fc2_b    = (const float*)d_in[33];

  float* ws = (float*)d_ws;
  float* x3c    = ws;                       // 1,179,648
  float* xact1  = x3c    + 1179648;         // 1,253,376 (padded GN1 act)
  float* h1     = xact1  + 1253376;         // 393,216
  float* xact2  = h1     + 393216;          // 417,792 (padded GN2 act)
  float* xpslot = xact2  + 417792;          // 393,216 (hosts Bp)
  float* x_cmaj = xpslot + 393216;          // 393,216
  float* z_t    = x_cmaj + 393216;          // 786,432
  float* xc     = z_t    + 786432;          // 786,432
  float* cpslot = xc     + 786432;          // 786,432 (hosts Cp)
  float* hole   = cpslot + 786432;          // 884,736 (dtr + Ssum)
  float* scanbuf= hole   + 884736;          // 3,145,728 (conv1 partials)
  float* ys_t   = scanbuf+ 3145728;         // 3,145,728 (conv2 partials + skip first)
  float* statsb = ys_t   + 3145728;         // psum1(768) psq1(768) psum2(384) psq2(384)
  float* psum1  = statsb;
  float* psq1   = statsb + 768;
  float* psum2  = statsb + 1536;
  float* psq2   = statsb + 1920;
  // aliases into dead regions (timeline-verified, same as R7/R8):
  float* part1  = scanbuf;          // conv1 partials (12 slots: scanbuf + ys_t[0..4))
  float* part2  = ys_t;             // conv2 partials slots 0-3; skip slots 4,5
  float* hend   = x3c;              // x3c+xact1 dead after k_gnact1_skip/conv1
  float* u_t    = h1;               // h1+xact2 dead after gnact2/conv2
  float* Bp     = xpslot;
  float* Cp     = cpslot;
  float* dtr    = hole;             // 98,304
  float* Ssum   = hole + 98304;     // 98,304

  k_ln2d<<<768, 256, 0, stream>>>(img, dz, sg, norm_g, norm_b, x3c, psum1, psq1);
  k_gnact1_skip<<<1536, 256, 0, stream>>>(x3c, psum1, psq1, gn1_g, gn1_b, skip_w,
                                          xact1, part2);
  k_conv1_split<<<2304, 256, 0, stream>>>(xact1, conv1_w, part1);
  k_reduce1<<<384, 256, 0, stream>>>(part1, conv1_b, h1, psum2, psq2);
  k_gnact_pad<<<6*CCH, 256, 0, stream>>>(h1, psum2, psq2, gn2_g, gn2_b, CCH, 64,
                                         1.f/(CCH*L2), 1e-5f, xact2);
  k_conv2_split<<<768, 256, 0, stream>>>(xact2, conv2_w, part2);
  k_red2_ln1_inproj<<<768, 256, 0, stream>>>(part2, conv2_b, skip_b, ln1_g, ln1_b, in_proj_w,
                                             x_cmaj, xc, z_t);
  k_xproj_dt<<<768, 256, 0, stream>>>(xc, dwconv_w, dwconv_b, x_proj_w, dtr, Bp, Cp, u_t);
  k_scan_part3<<<768, 256, 0, stream>>>(dtr, dt_proj_w, dt_proj_b, u_t, Bp, A_logs, hend, Ssum);
  k_scan_y3<<<768, 256, 0, stream>>>(dtr, dt_proj_w, dt_proj_b, u_t, Bp, Cp, A_logs, Ds,
                                     hend, Ssum, ys_t);
  k_tail<<<768, 256, 0, stream>>>(ys_t, z_t, out_norm_g, out_norm_b, out_proj_w, x_cmaj,
                                  ln2_g, ln2_b, fc1_w, fc1_b, fc2_w, fc2_b, (float*)d_out);
}